// Round 1
// baseline (73100.183 us; speedup 1.0000x reference)
//
#include <hip/hip_runtime.h>
#include <hip/hip_bf16.h>
#include <math.h>

#define DEV static __device__ __forceinline__

DEV float rl(float v, int i){ return __uint_as_float(__builtin_amdgcn_readlane(__float_as_uint(v), i)); }

// ---- workspace layout (bytes) ----
static constexpr size_t OFF_H     = 0;                    // 8192*1024*4 = 33554432
static constexpr size_t OFF_FEATS = 33554432;             // 8192*5*4    = 163840
static constexpr size_t OFF_BPS   = OFF_FEATS + 163840;   // 8192*5*4 int
static constexpr size_t OFF_FC    = OFF_BPS + 163840;     // 256*5*4
static constexpr size_t OFF_ECH   = OFF_FC + 5120;        // 256*4
static constexpr size_t OFF_EBEST = OFF_ECH + 1024;       // 256
static constexpr size_t OFF_HBUF  = OFF_EBEST + 256;      // 2*1024*4
static constexpr size_t OFF_SEQ   = OFF_HBUF + 8192;      // 64*4

// =====================================================================
// K2: persistent BiLSTM. 64 blocks: blocks 0..31 forward, 32..63 backward.
// Block (d,k) owns hidden units [k*16, k*16+16). 256 threads = 4 waves,
// wave w owns h-cols [w*128,w*128+128) and emb-cols [w*192,w*192+192).
// Lane l <-> local gate-row j=l: unit u=l>>2, gate g=l&3 (i,f,g,o).
// =====================================================================
__global__ __launch_bounds__(256,1) void lstm_k(
    const float* __restrict__ emb,
    const float* __restrict__ whhf, const float* __restrict__ whhb,
    const float* __restrict__ wihf, const float* __restrict__ wihb,
    const float* __restrict__ bihf, const float* __restrict__ bhhf,
    const float* __restrict__ bihb, const float* __restrict__ bhhb,
    const float* __restrict__ h0f, const float* __restrict__ c0f,
    const float* __restrict__ h0b, const float* __restrict__ c0b,
    float* __restrict__ H, float* __restrict__ hbuf, int* __restrict__ seq)
{
  const int b  = blockIdx.x;
  const int d  = b >> 5;       // direction
  const int k  = b & 31;       // unit-group
  const int tid = threadIdx.x;
  const int w  = tid >> 6;     // wave
  const int l  = tid & 63;     // lane

  const float* whh = d ? whhb : whhf;
  const float* wih = d ? wihb : wihf;
  const int grow = (l&3)*512 + k*16 + (l>>2);   // global gate-row in [0,2048)

  // ---- resident weights in VGPRs ----
  float wr[128];
  {
    const float4* p = reinterpret_cast<const float4*>(whh + (size_t)grow*512 + w*128);
    #pragma unroll
    for (int j=0;j<32;j++){ float4 v=p[j]; wr[4*j]=v.x; wr[4*j+1]=v.y; wr[4*j+2]=v.z; wr[4*j+3]=v.w; }
  }
  float wi[192];
  {
    const float4* p = reinterpret_cast<const float4*>(wih + (size_t)grow*768 + w*192);
    #pragma unroll
    for (int j=0;j<48;j++){ float4 v=p[j]; wi[4*j]=v.x; wi[4*j+1]=v.y; wi[4*j+2]=v.z; wi[4*j+3]=v.w; }
  }
  const float bias = (d?bihb:bihf)[grow] + (d?bhhb:bhhf)[grow];

  const float* h0 = d ? h0b : h0f;
  float hv0 = h0[w*128 + l];
  float hv1 = h0[w*128 + 64 + l];
  float c   = (d?c0b:c0f)[k*16 + (l>>2)];

  __shared__ float part[4][64];

#define EPART(X0,X1,X2,B0,B1_,B2_,B3_) \
  _Pragma("unroll") for (int i=0;i<64;i+=4){ \
    B0 =fmaf(rl(X0,i+0),wi[i+0],B0 ); B1_=fmaf(rl(X0,i+1),wi[i+1],B1_); \
    B2_=fmaf(rl(X0,i+2),wi[i+2],B2_); B3_=fmaf(rl(X0,i+3),wi[i+3],B3_); } \
  _Pragma("unroll") for (int i=0;i<64;i+=4){ \
    B0 =fmaf(rl(X1,i+0),wi[64+i+0],B0 ); B1_=fmaf(rl(X1,i+1),wi[64+i+1],B1_); \
    B2_=fmaf(rl(X1,i+2),wi[64+i+2],B2_); B3_=fmaf(rl(X1,i+3),wi[64+i+3],B3_); } \
  _Pragma("unroll") for (int i=0;i<64;i+=4){ \
    B0 =fmaf(rl(X2,i+0),wi[128+i+0],B0 ); B1_=fmaf(rl(X2,i+1),wi[128+i+1],B1_); \
    B2_=fmaf(rl(X2,i+2),wi[128+i+2],B2_); B3_=fmaf(rl(X2,i+3),wi[128+i+3],B3_); }

  // ---- prologue: e-part for t(0), emb regs for t(1) ----
  float acc_e;
  {
    const int tA = d ? 8191 : 0;
    const float* e = emb + (size_t)tA*768 + w*192 + l;
    float x0=e[0], x1=e[64], x2=e[128];
    float b0=0.f,b1=0.f,b2=0.f,b3=0.f;
    EPART(x0,x1,x2,b0,b1,b2,b3);
    acc_e = (b0+b1)+(b2+b3);
  }
  float ev0,ev1,ev2;
  {
    const int tB = d ? 8190 : 1;
    const float* e = emb + (size_t)tB*768 + w*192 + l;
    ev0=e[0]; ev1=e[64]; ev2=e[128];
  }

  for (int s=0; s<8192; s++){
    const int t = d ? (8191-s) : s;
    // ---- h-part GEMV (recurrent matvec), seeded with acc_e ----
    float a0=acc_e, a1=0.f, a2=0.f, a3=0.f;
    #pragma unroll
    for (int i=0;i<64;i+=4){
      a0=fmaf(rl(hv0,i+0),wr[i+0],a0); a1=fmaf(rl(hv0,i+1),wr[i+1],a1);
      a2=fmaf(rl(hv0,i+2),wr[i+2],a2); a3=fmaf(rl(hv0,i+3),wr[i+3],a3);
    }
    #pragma unroll
    for (int i=0;i<64;i+=4){
      a0=fmaf(rl(hv1,i+0),wr[64+i+0],a0); a1=fmaf(rl(hv1,i+1),wr[64+i+1],a1);
      a2=fmaf(rl(hv1,i+2),wr[64+i+2],a2); a3=fmaf(rl(hv1,i+3),wr[64+i+3],a3);
    }
    part[w][l] = (a0+a1)+(a2+a3);
    __syncthreads();

    if (w==0){
      float r = part[0][l]+part[1][l]+part[2][l]+part[3][l] + bias;
      const bool isg = ((l&3)==2);
      float xx = isg ? 2.f*r : r;
      float sg = 1.f/(1.f + expf(-xx));       // sigmoid
      float a  = isg ? fmaf(2.f,sg,-1.f) : sg; // tanh via 2*sig(2x)-1 for g-gate
      const int lb = l & ~3;
      float ig = __shfl(a, lb);
      float fg = __shfl(a, lb+1);
      float gg = __shfl(a, lb+2);
      float og = __shfl(a, lb+3);
      if ((l&3)==0){
        c = fmaf(fg, c, ig*gg);
        float h = og * tanhf(c);
        const int unit = k*16 + (l>>2);
        __hip_atomic_store(hbuf + ((s&1)<<10) + d*512 + unit, h,
                           __ATOMIC_RELAXED, __HIP_MEMORY_SCOPE_AGENT);
        H[(size_t)t*1024 + d*512 + unit] = h;
      }
      if (tid==0)
        __hip_atomic_store(seq + b, s+1, __ATOMIC_RELEASE, __HIP_MEMORY_SCOPE_AGENT);
    }

    if (s<8191){
      // wait for all 32 WGs of this direction to publish h(s)
      if (l<32){
        const int* sp = seq + d*32 + l;
        while (__hip_atomic_load(sp, __ATOMIC_ACQUIRE, __HIP_MEMORY_SCOPE_AGENT) <= s)
          __builtin_amdgcn_s_sleep(1);
      }
      const int hb = ((s&1)<<10) + d*512 + w*128 + l;
      float nh0 = __hip_atomic_load(hbuf+hb,    __ATOMIC_RELAXED, __HIP_MEMORY_SCOPE_AGENT);
      float nh1 = __hip_atomic_load(hbuf+hb+64, __ATOMIC_RELAXED, __HIP_MEMORY_SCOPE_AGENT);
      float nx0=0.f, nx1=0.f, nx2=0.f;
      if (s<8190){
        const int t2 = d ? (8189-s) : (s+2);
        const float* e = emb + (size_t)t2*768 + w*192 + l;
        nx0=e[0]; nx1=e[64]; nx2=e[128];
      }
      // e-part for next step overlaps the h-load latency
      float b0=0.f,b1=0.f,b2=0.f,b3=0.f;
      EPART(ev0,ev1,ev2,b0,b1,b2,b3);
      acc_e = (b0+b1)+(b2+b3);
      ev0=nx0; ev1=nx1; ev2=nx2;
      hv0=nh0; hv1=nh1;
    }
  }
#undef EPART
}

// =====================================================================
// K3: feats[t][n] = H[t][:] . w_tag[n][:] + b_tag[n]   (wave per row)
// =====================================================================
__global__ void feats_k(const float* __restrict__ H, const float* __restrict__ wtag,
                        const float* __restrict__ btag, float* __restrict__ feats)
{
  const int r = blockIdx.x*4 + (threadIdx.x>>6);
  const int l = threadIdx.x & 63;
  const float* hrow = H + (size_t)r*1024;
  float hv[16];
  #pragma unroll
  for (int j=0;j<16;j++) hv[j] = hrow[j*64 + l];
  #pragma unroll
  for (int n=0;n<5;n++){
    const float* wrow = wtag + n*1024;
    float acc = 0.f;
    #pragma unroll
    for (int j=0;j<16;j++) acc = fmaf(hv[j], wrow[j*64+l], acc);
    #pragma unroll
    for (int off=32; off; off>>=1) acc += __shfl_xor(acc, off);
    if (l==0) feats[r*5+n] = acc + btag[n];
  }
}

// =====================================================================
// V: sequential Viterbi forward (exact fp32, reference association order).
// lanes: l<25 active, n=l/5 (next tag), p=l%5 (prev tag).
// =====================================================================
__global__ void vit_fv(const float* __restrict__ feats, const float* __restrict__ trans,
                       int* __restrict__ bps, float* __restrict__ out, int* __restrict__ ebest)
{
  const int l = threadIdx.x & 63;
  const bool active = (l < 25);
  const int n = l/5;
  float tr0=0,tr1=0,tr2=0,tr3=0,tr4=0;
  if (active){ tr0=trans[n*5+0]; tr1=trans[n*5+1]; tr2=trans[n*5+2]; tr3=trans[n*5+3]; tr4=trans[n*5+4]; }
  const float NEG = -10000.0f;
  float fv0=NEG, fv1=NEG, fv2=NEG, fv3=0.f, fv4=NEG;   // START=3

  float ring[16];
  #pragma unroll
  for (int j=0;j<16;j++) ring[j] = active ? feats[j*5+n] : 0.f;

  for (int tb=0; tb<8192; tb+=16){
    #pragma unroll
    for (int j=0;j<16;j++){
      const int t = tb + j;
      float ft = ring[j];
      float m = fv0 + tr0; int a = 0; float v;
      v = fv1 + tr1; if (v > m){ m=v; a=1; }
      v = fv2 + tr2; if (v > m){ m=v; a=2; }
      v = fv3 + tr3; if (v > m){ m=v; a=3; }
      v = fv4 + tr4; if (v > m){ m=v; a=4; }
      float fnew = m + ft;
      if (active && (l%5)==0) bps[t*5+n] = a;
      fv0 = __shfl(fnew, 0);  fv1 = __shfl(fnew, 5);  fv2 = __shfl(fnew, 10);
      fv3 = __shfl(fnew, 15); fv4 = __shfl(fnew, 20);
      const int tf = t + 16;
      ring[j] = (active && tf < 8192) ? feats[tf*5+n] : 0.f;
    }
  }
  if (l==0){
    // terminal = fv + transitions[STOP=4][:]
    float t0=trans[20], t1=trans[21], t2=trans[22], t3=trans[23], t4=trans[24];
    float m = fv0 + t0; int a = 0; float v;
    v = fv1 + t1; if (v > m){ m=v; a=1; }
    v = fv2 + t2; if (v > m){ m=v; a=2; }
    v = fv3 + t3; if (v > m){ m=v; a=3; }
    v = fv4 + t4; if (v > m){ m=v; a=4; }
    out[0] = m;       // path_score
    ebest[0] = a;
  }
}

// =====================================================================
// Backtrack: exact integer parallel scan over 256 chunks of 32 steps.
// =====================================================================
__global__ void bt_maps(const int* __restrict__ bps, int* __restrict__ Fc)
{
  __shared__ int sm[160];
  const int c = blockIdx.x, tid = threadIdx.x;
  for (int idx=tid; idx<160; idx+=64) sm[idx] = bps[c*160+idx];
  __syncthreads();
  if (tid<5){
    int cur = tid;
    for (int j=31;j>=0;j--) cur = sm[j*5+cur];
    Fc[c*5+tid] = cur;   // tag@(c*32-1) given tag@(c*32+31)=tid
  }
}

__global__ void bt_seq(const int* __restrict__ Fc, const int* __restrict__ ebest,
                       int* __restrict__ echunk)
{
  __shared__ int sm[1280];
  const int tid = threadIdx.x;
  for (int idx=tid; idx<1280; idx+=64) sm[idx]=Fc[idx];
  __syncthreads();
  if (tid==0){
    int e = ebest[0];
    for (int c=255;c>=0;c--){ echunk[c]=e; e = sm[c*5+e]; }
  }
}

__global__ void bt_emit(const int* __restrict__ bps, const int* __restrict__ echunk,
                        float* __restrict__ out)
{
  __shared__ int sm[160];
  const int c=blockIdx.x, tid=threadIdx.x;
  for (int idx=tid; idx<160; idx+=64) sm[idx]=bps[c*160+idx];
  __syncthreads();
  if (tid==0){
    int tag = echunk[c];
    out[1 + c*32 + 31] = (float)tag;
    for (int j=31;j>=1;j--){ tag = sm[j*5+tag]; out[1 + c*32 + j-1] = (float)tag; }
  }
}

// =====================================================================
extern "C" void kernel_launch(void* const* d_in, const int* in_sizes, int n_in,
                              void* d_out, int out_size, void* d_ws, size_t ws_size,
                              hipStream_t stream)
{
  (void)in_sizes; (void)n_in; (void)out_size; (void)ws_size;
  const float* emb  = (const float*)d_in[0];
  const float* wihf = (const float*)d_in[1];
  const float* whhf = (const float*)d_in[2];
  const float* bihf = (const float*)d_in[3];
  const float* bhhf = (const float*)d_in[4];
  const float* wihb = (const float*)d_in[5];
  const float* whhb = (const float*)d_in[6];
  const float* bihb = (const float*)d_in[7];
  const float* bhhb = (const float*)d_in[8];
  const float* wtag = (const float*)d_in[9];
  const float* btag = (const float*)d_in[10];
  const float* h0f  = (const float*)d_in[11];
  const float* c0f  = (const float*)d_in[12];
  const float* h0b  = (const float*)d_in[13];
  const float* c0b  = (const float*)d_in[14];
  const float* trans= (const float*)d_in[15];
  float* out = (float*)d_out;

  char* ws = (char*)d_ws;
  float* H      = (float*)(ws + OFF_H);
  float* feats  = (float*)(ws + OFF_FEATS);
  int*   bps    = (int*)  (ws + OFF_BPS);
  int*   Fc     = (int*)  (ws + OFF_FC);
  int*   echunk = (int*)  (ws + OFF_ECH);
  int*   ebest  = (int*)  (ws + OFF_EBEST);
  float* hbuf   = (float*)(ws + OFF_HBUF);
  int*   seq    = (int*)  (ws + OFF_SEQ);

  hipMemsetAsync(seq, 0, 256, stream);   // reset sync flags every launch (graph-safe)

  lstm_k<<<64, 256, 0, stream>>>(emb, whhf, whhb, wihf, wihb,
                                 bihf, bhhf, bihb, bhhb,
                                 h0f, c0f, h0b, c0b, H, hbuf, seq);
  feats_k<<<2048, 256, 0, stream>>>(H, wtag, btag, feats);
  vit_fv<<<1, 64, 0, stream>>>(feats, trans, bps, out, ebest);
  bt_maps<<<256, 64, 0, stream>>>(bps, Fc);
  bt_seq<<<1, 64, 0, stream>>>(Fc, ebest, echunk);
  bt_emit<<<256, 64, 0, stream>>>(bps, echunk, out);
}

// Round 2
// 23220.711 us; speedup vs baseline: 3.1481x; 3.1481x over previous
//
#include <hip/hip_runtime.h>
#include <hip/hip_bf16.h>
#include <math.h>

#define DEV static __device__ __forceinline__

DEV float rl(float v, int i){ return __uint_as_float(__builtin_amdgcn_readlane(__float_as_uint(v), i)); }

// ---- workspace layout (bytes) ----
static constexpr size_t OFF_H     = 0;                    // 8192*1024*4 = 33554432
static constexpr size_t OFF_FEATS = 33554432;             // 8192*5*4    = 163840
static constexpr size_t OFF_BPS   = OFF_FEATS + 163840;   // 8192*5*4 int
static constexpr size_t OFF_FC    = OFF_BPS + 163840;     // 256*5*4
static constexpr size_t OFF_ECH   = OFF_FC + 5120;        // 256*4
static constexpr size_t OFF_EBEST = OFF_ECH + 1024;       // 256
static constexpr size_t OFF_HBUF  = OFF_EBEST + 256;      // 2*1024*8 = 16384 (u64, 8-aligned)

// =====================================================================
// K2: persistent BiLSTM. 64 blocks: blocks 0..31 forward, 32..63 backward.
// Block (d,k) owns hidden units [k*16, k*16+16). 256 threads = 4 waves,
// wave w owns h-cols [w*128,w*128+128) and emb-cols [w*192,w*192+192).
// Sync: h published as relaxed agent-scope u64 (tag<<32 | h_bits) — no
// acquire/release (those emit per-XCD L2 wb/inv each poll = round-1's 7us/step).
// =====================================================================
__global__ __launch_bounds__(256,1) void lstm_k(
    const float* __restrict__ emb,
    const float* __restrict__ whhf, const float* __restrict__ whhb,
    const float* __restrict__ wihf, const float* __restrict__ wihb,
    const float* __restrict__ bihf, const float* __restrict__ bhhf,
    const float* __restrict__ bihb, const float* __restrict__ bhhb,
    const float* __restrict__ h0f, const float* __restrict__ c0f,
    const float* __restrict__ h0b, const float* __restrict__ c0b,
    float* __restrict__ H, unsigned long long* __restrict__ hbuf)
{
  const int b  = blockIdx.x;
  const int d  = b >> 5;       // direction
  const int k  = b & 31;       // unit-group
  const int tid = threadIdx.x;
  const int w  = tid >> 6;     // wave
  const int l  = tid & 63;     // lane

  const float* whh = d ? whhb : whhf;
  const float* wih = d ? wihb : wihf;
  const int grow = (l&3)*512 + k*16 + (l>>2);   // global gate-row in [0,2048)

  // ---- resident weights in VGPRs ----
  float wr[128];
  {
    const float4* p = reinterpret_cast<const float4*>(whh + (size_t)grow*512 + w*128);
    #pragma unroll
    for (int j=0;j<32;j++){ float4 v=p[j]; wr[4*j]=v.x; wr[4*j+1]=v.y; wr[4*j+2]=v.z; wr[4*j+3]=v.w; }
  }
  float wi[192];
  {
    const float4* p = reinterpret_cast<const float4*>(wih + (size_t)grow*768 + w*192);
    #pragma unroll
    for (int j=0;j<48;j++){ float4 v=p[j]; wi[4*j]=v.x; wi[4*j+1]=v.y; wi[4*j+2]=v.z; wi[4*j+3]=v.w; }
  }
  const float bias = (d?bihb:bihf)[grow] + (d?bhhb:bhhf)[grow];

  const float* h0 = d ? h0b : h0f;
  float hv0 = h0[w*128 + l];
  float hv1 = h0[w*128 + 64 + l];
  float c   = (d?c0b:c0f)[k*16 + (l>>2)];

  __shared__ float part[2][4][64];   // double-buffered cross-wave partials

#define EPART(X0,X1,X2,B0,B1_,B2_,B3_) \
  _Pragma("unroll") for (int i=0;i<64;i+=4){ \
    B0 =fmaf(rl(X0,i+0),wi[i+0],B0 ); B1_=fmaf(rl(X0,i+1),wi[i+1],B1_); \
    B2_=fmaf(rl(X0,i+2),wi[i+2],B2_); B3_=fmaf(rl(X0,i+3),wi[i+3],B3_); } \
  _Pragma("unroll") for (int i=0;i<64;i+=4){ \
    B0 =fmaf(rl(X1,i+0),wi[64+i+0],B0 ); B1_=fmaf(rl(X1,i+1),wi[64+i+1],B1_); \
    B2_=fmaf(rl(X1,i+2),wi[64+i+2],B2_); B3_=fmaf(rl(X1,i+3),wi[64+i+3],B3_); } \
  _Pragma("unroll") for (int i=0;i<64;i+=4){ \
    B0 =fmaf(rl(X2,i+0),wi[128+i+0],B0 ); B1_=fmaf(rl(X2,i+1),wi[128+i+1],B1_); \
    B2_=fmaf(rl(X2,i+2),wi[128+i+2],B2_); B3_=fmaf(rl(X2,i+3),wi[128+i+3],B3_); }

  // ---- prologue: e-part for t(0), emb regs for t(1) ----
  float acc_e;
  {
    const int tA = d ? 8191 : 0;
    const float* e = emb + (size_t)tA*768 + w*192 + l;
    float x0=e[0], x1=e[64], x2=e[128];
    float b0=0.f,b1=0.f,b2=0.f,b3=0.f;
    EPART(x0,x1,x2,b0,b1,b2,b3);
    acc_e = (b0+b1)+(b2+b3);
  }
  float ev0,ev1,ev2;
  {
    const int tB = d ? 8190 : 1;
    const float* e = emb + (size_t)tB*768 + w*192 + l;
    ev0=e[0]; ev1=e[64]; ev2=e[128];
  }

  for (int s=0; s<8192; s++){
    const int t  = d ? (8191-s) : s;
    const int pb = s & 1;
    // ---- h-part GEMV (recurrent matvec), seeded with acc_e ----
    float a0=acc_e, a1=0.f, a2=0.f, a3=0.f;
    #pragma unroll
    for (int i=0;i<64;i+=4){
      a0=fmaf(rl(hv0,i+0),wr[i+0],a0); a1=fmaf(rl(hv0,i+1),wr[i+1],a1);
      a2=fmaf(rl(hv0,i+2),wr[i+2],a2); a3=fmaf(rl(hv0,i+3),wr[i+3],a3);
    }
    #pragma unroll
    for (int i=0;i<64;i+=4){
      a0=fmaf(rl(hv1,i+0),wr[64+i+0],a0); a1=fmaf(rl(hv1,i+1),wr[64+i+1],a1);
      a2=fmaf(rl(hv1,i+2),wr[64+i+2],a2); a3=fmaf(rl(hv1,i+3),wr[64+i+3],a3);
    }
    part[pb][w][l] = (a0+a1)+(a2+a3);
    __syncthreads();

    if (w==0){
      float r = part[pb][0][l]+part[pb][1][l]+part[pb][2][l]+part[pb][3][l] + bias;
      const bool isg = ((l&3)==2);
      float xx = isg ? 2.f*r : r;
      float sg = 1.f/(1.f + expf(-xx));        // sigmoid
      float a  = isg ? fmaf(2.f,sg,-1.f) : sg; // tanh via 2*sig(2x)-1 for g-gate
      const int lb = l & ~3;
      float ig = __shfl(a, lb);
      float fg = __shfl(a, lb+1);
      float gg = __shfl(a, lb+2);
      float og = __shfl(a, lb+3);
      if ((l&3)==0){
        c = fmaf(fg, c, ig*gg);
        float h = og * tanhf(c);
        const int unit = k*16 + (l>>2);
        unsigned long long pk = ((unsigned long long)(unsigned)(s+1) << 32)
                              | (unsigned long long)__float_as_uint(h);
        __hip_atomic_store(hbuf + (pb<<10) + d*512 + unit, pk,
                           __ATOMIC_RELAXED, __HIP_MEMORY_SCOPE_AGENT);
        H[(size_t)t*1024 + d*512 + unit] = h;
      }
    }

    if (s<8191){
      // prefetch emb for t+2 (independent, in flight during EPART)
      float nx0=0.f, nx1=0.f, nx2=0.f;
      if (s<8190){
        const int t2 = d ? (8189-s) : (s+2);
        const float* e = emb + (size_t)t2*768 + w*192 + l;
        nx0=e[0]; nx1=e[64]; nx2=e[128];
      }
      // e-part for step s+1 — overlaps the publish->MALL propagation
      float b0=0.f,b1=0.f,b2=0.f,b3=0.f;
      EPART(ev0,ev1,ev2,b0,b1,b2,b3);
      acc_e = (b0+b1)+(b2+b3);
      ev0=nx0; ev1=nx1; ev2=nx2;

      // poll own two (tag,h) pairs — relaxed, no cache maintenance
      const unsigned long long* hp = hbuf + (pb<<10) + d*512 + w*128 + l;
      unsigned long long p0, p1;
      const unsigned want = (unsigned)(s+1);
      do {
        p0 = __hip_atomic_load(hp,    __ATOMIC_RELAXED, __HIP_MEMORY_SCOPE_AGENT);
        p1 = __hip_atomic_load(hp+64, __ATOMIC_RELAXED, __HIP_MEMORY_SCOPE_AGENT);
      } while ((unsigned)(p0>>32) < want || (unsigned)(p1>>32) < want);
      hv0 = __uint_as_float((unsigned)p0);
      hv1 = __uint_as_float((unsigned)p1);
    }
  }
#undef EPART
}

// =====================================================================
// K3: feats[t][n] = H[t][:] . w_tag[n][:] + b_tag[n]   (wave per row)
// =====================================================================
__global__ void feats_k(const float* __restrict__ H, const float* __restrict__ wtag,
                        const float* __restrict__ btag, float* __restrict__ feats)
{
  const int r = blockIdx.x*4 + (threadIdx.x>>6);
  const int l = threadIdx.x & 63;
  const float* hrow = H + (size_t)r*1024;
  float hv[16];
  #pragma unroll
  for (int j=0;j<16;j++) hv[j] = hrow[j*64 + l];
  #pragma unroll
  for (int n=0;n<5;n++){
    const float* wrow = wtag + n*1024;
    float acc = 0.f;
    #pragma unroll
    for (int j=0;j<16;j++) acc = fmaf(hv[j], wrow[j*64+l], acc);
    #pragma unroll
    for (int off=32; off; off>>=1) acc += __shfl_xor(acc, off);
    if (l==0) feats[r*5+n] = acc + btag[n];
  }
}

// =====================================================================
// V: sequential Viterbi forward (exact fp32, reference association order).
// =====================================================================
__global__ void vit_fv(const float* __restrict__ feats, const float* __restrict__ trans,
                       int* __restrict__ bps, float* __restrict__ out, int* __restrict__ ebest)
{
  const int l = threadIdx.x & 63;
  const bool active = (l < 25);
  const int n = l/5;
  float tr0=0,tr1=0,tr2=0,tr3=0,tr4=0;
  if (active){ tr0=trans[n*5+0]; tr1=trans[n*5+1]; tr2=trans[n*5+2]; tr3=trans[n*5+3]; tr4=trans[n*5+4]; }
  const float NEG = -10000.0f;
  float fv0=NEG, fv1=NEG, fv2=NEG, fv3=0.f, fv4=NEG;   // START=3

  float ring[16];
  #pragma unroll
  for (int j=0;j<16;j++) ring[j] = active ? feats[j*5+n] : 0.f;

  for (int tb=0; tb<8192; tb+=16){
    #pragma unroll
    for (int j=0;j<16;j++){
      const int t = tb + j;
      float ft = ring[j];
      float m = fv0 + tr0; int a = 0; float v;
      v = fv1 + tr1; if (v > m){ m=v; a=1; }
      v = fv2 + tr2; if (v > m){ m=v; a=2; }
      v = fv3 + tr3; if (v > m){ m=v; a=3; }
      v = fv4 + tr4; if (v > m){ m=v; a=4; }
      float fnew = m + ft;
      if (active && (l%5)==0) bps[t*5+n] = a;
      fv0 = __shfl(fnew, 0);  fv1 = __shfl(fnew, 5);  fv2 = __shfl(fnew, 10);
      fv3 = __shfl(fnew, 15); fv4 = __shfl(fnew, 20);
      const int tf = t + 16;
      ring[j] = (active && tf < 8192) ? feats[tf*5+n] : 0.f;
    }
  }
  if (l==0){
    float t0=trans[20], t1=trans[21], t2=trans[22], t3=trans[23], t4=trans[24];
    float m = fv0 + t0; int a = 0; float v;
    v = fv1 + t1; if (v > m){ m=v; a=1; }
    v = fv2 + t2; if (v > m){ m=v; a=2; }
    v = fv3 + t3; if (v > m){ m=v; a=3; }
    v = fv4 + t4; if (v > m){ m=v; a=4; }
    out[0] = m;       // path_score
    ebest[0] = a;
  }
}

// =====================================================================
// Backtrack: exact integer parallel scan over 256 chunks of 32 steps.
// =====================================================================
__global__ void bt_maps(const int* __restrict__ bps, int* __restrict__ Fc)
{
  __shared__ int sm[160];
  const int c = blockIdx.x, tid = threadIdx.x;
  for (int idx=tid; idx<160; idx+=64) sm[idx] = bps[c*160+idx];
  __syncthreads();
  if (tid<5){
    int cur = tid;
    for (int j=31;j>=0;j--) cur = sm[j*5+cur];
    Fc[c*5+tid] = cur;
  }
}

__global__ void bt_seq(const int* __restrict__ Fc, const int* __restrict__ ebest,
                       int* __restrict__ echunk)
{
  __shared__ int sm[1280];
  const int tid = threadIdx.x;
  for (int idx=tid; idx<1280; idx+=64) sm[idx]=Fc[idx];
  __syncthreads();
  if (tid==0){
    int e = ebest[0];
    for (int c=255;c>=0;c--){ echunk[c]=e; e = sm[c*5+e]; }
  }
}

__global__ void bt_emit(const int* __restrict__ bps, const int* __restrict__ echunk,
                        float* __restrict__ out)
{
  __shared__ int sm[160];
  const int c=blockIdx.x, tid=threadIdx.x;
  for (int idx=tid; idx<160; idx+=64) sm[idx]=bps[c*160+idx];
  __syncthreads();
  if (tid==0){
    int tag = echunk[c];
    out[1 + c*32 + 31] = (float)tag;
    for (int j=31;j>=1;j--){ tag = sm[j*5+tag]; out[1 + c*32 + j-1] = (float)tag; }
  }
}

// =====================================================================
extern "C" void kernel_launch(void* const* d_in, const int* in_sizes, int n_in,
                              void* d_out, int out_size, void* d_ws, size_t ws_size,
                              hipStream_t stream)
{
  (void)in_sizes; (void)n_in; (void)out_size; (void)ws_size;
  const float* emb  = (const float*)d_in[0];
  const float* wihf = (const float*)d_in[1];
  const float* whhf = (const float*)d_in[2];
  const float* bihf = (const float*)d_in[3];
  const float* bhhf = (const float*)d_in[4];
  const float* wihb = (const float*)d_in[5];
  const float* whhb = (const float*)d_in[6];
  const float* bihb = (const float*)d_in[7];
  const float* bhhb = (const float*)d_in[8];
  const float* wtag = (const float*)d_in[9];
  const float* btag = (const float*)d_in[10];
  const float* h0f  = (const float*)d_in[11];
  const float* c0f  = (const float*)d_in[12];
  const float* h0b  = (const float*)d_in[13];
  const float* c0b  = (const float*)d_in[14];
  const float* trans= (const float*)d_in[15];
  float* out = (float*)d_out;

  char* ws = (char*)d_ws;
  float* H      = (float*)(ws + OFF_H);
  float* feats  = (float*)(ws + OFF_FEATS);
  int*   bps    = (int*)  (ws + OFF_BPS);
  int*   Fc     = (int*)  (ws + OFF_FC);
  int*   echunk = (int*)  (ws + OFF_ECH);
  int*   ebest  = (int*)  (ws + OFF_EBEST);
  unsigned long long* hbuf = (unsigned long long*)(ws + OFF_HBUF);

  hipMemsetAsync(hbuf, 0, 2*1024*8, stream);   // clear (tag,h) pairs every launch

  lstm_k<<<64, 256, 0, stream>>>(emb, whhf, whhb, wihf, wihb,
                                 bihf, bhhf, bihb, bhhb,
                                 h0f, c0f, h0b, c0b, H, hbuf);
  feats_k<<<2048, 256, 0, stream>>>(H, wtag, btag, feats);
  vit_fv<<<1, 64, 0, stream>>>(feats, trans, bps, out, ebest);
  bt_maps<<<256, 64, 0, stream>>>(bps, Fc);
  bt_seq<<<1, 64, 0, stream>>>(Fc, ebest, echunk);
  bt_emit<<<256, 64, 0, stream>>>(bps, echunk, out);
}

// Round 3
// 23070.671 us; speedup vs baseline: 3.1685x; 1.0065x over previous
//
#include <hip/hip_runtime.h>
#include <hip/hip_bf16.h>
#include <math.h>

#define DEV static __device__ __forceinline__

DEV float rl(float v, int i){ return __uint_as_float(__builtin_amdgcn_readlane(__float_as_uint(v), i)); }

typedef float f32x32 __attribute__((ext_vector_type(32)));

// ---- workspace layout (bytes) ----
static constexpr size_t OFF_H     = 0;                    // 8192*1024*4 = 33554432
static constexpr size_t OFF_FEATS = 33554432;             // 8192*5*4    = 163840
static constexpr size_t OFF_BPS   = OFF_FEATS + 163840;   // 8192*5*4 int
static constexpr size_t OFF_FC    = OFF_BPS + 163840;     // 256*5*4
static constexpr size_t OFF_ECH   = OFF_FC + 5120;        // 256*4
static constexpr size_t OFF_EBEST = OFF_ECH + 1024;       // 256
static constexpr size_t OFF_HBUF  = OFF_EBEST + 256;      // 2*1024*8 = 16384 (u64, 8-aligned)

// =====================================================================
// K2: persistent BiLSTM. 64 blocks: blocks 0..31 forward, 32..63 backward.
// Block (d,k) owns hidden units [k*16, k*16+16). 256 threads = 4 waves,
// wave w owns h-cols [w*128,w*128+128) and emb-cols [w*192,w*192+192).
// Weights as NAMED ext_vector_type(32) SSA values -> true VGPR residency
// (round-2's float[320] arrays fell to scratch: VGPR_Count was 184 < 320).
// Sync: h published as relaxed agent-scope u64 (tag<<32 | h_bits).
// =====================================================================
__global__ __launch_bounds__(256,1) void lstm_k(
    const float* __restrict__ emb,
    const float* __restrict__ whhf, const float* __restrict__ whhb,
    const float* __restrict__ wihf, const float* __restrict__ wihb,
    const float* __restrict__ bihf, const float* __restrict__ bhhf,
    const float* __restrict__ bihb, const float* __restrict__ bhhb,
    const float* __restrict__ h0f, const float* __restrict__ c0f,
    const float* __restrict__ h0b, const float* __restrict__ c0b,
    float* __restrict__ H, unsigned long long* __restrict__ hbuf)
{
  const int b  = blockIdx.x;
  const int d  = b >> 5;       // direction
  const int k  = b & 31;       // unit-group
  const int tid = threadIdx.x;
  const int w  = tid >> 6;     // wave
  const int l  = tid & 63;     // lane

  const float* whh = d ? whhb : whhf;
  const float* wih = d ? wihb : wihf;
  const int grow = (l&3)*512 + k*16 + (l>>2);   // global gate-row in [0,2048)

  // ---- resident weights in VGPRs (named vector SSA values, no alloca) ----
  const float* pr = whh + (size_t)grow*512 + w*128;
  const f32x32 wr0 = *reinterpret_cast<const f32x32*>(pr);
  const f32x32 wr1 = *reinterpret_cast<const f32x32*>(pr+32);
  const f32x32 wr2 = *reinterpret_cast<const f32x32*>(pr+64);
  const f32x32 wr3 = *reinterpret_cast<const f32x32*>(pr+96);
  const float* pi = wih + (size_t)grow*768 + w*192;
  const f32x32 wi0 = *reinterpret_cast<const f32x32*>(pi);
  const f32x32 wi1 = *reinterpret_cast<const f32x32*>(pi+32);
  const f32x32 wi2 = *reinterpret_cast<const f32x32*>(pi+64);
  const f32x32 wi3 = *reinterpret_cast<const f32x32*>(pi+96);
  const f32x32 wi4 = *reinterpret_cast<const f32x32*>(pi+128);
  const f32x32 wi5 = *reinterpret_cast<const f32x32*>(pi+160);

  const float bias = (d?bihb:bihf)[grow] + (d?bhhb:bhhf)[grow];

  const float* h0 = d ? h0b : h0f;
  float hv0 = h0[w*128 + l];
  float hv1 = h0[w*128 + 64 + l];
  float c   = (d?c0b:c0f)[k*16 + (l>>2)];

  __shared__ float part[2][4][64];   // double-buffered cross-wave partials

  // 32 fma into striped accumulators; lane source = X lanes OFF..OFF+31,
  // weight = vector W elements 0..31. Order matches round-2 bit-exactly.
#define DOT32(X, OFF, W, B0, B1_, B2_, B3_) \
  _Pragma("unroll") for (int i=0;i<32;i+=4){ \
    B0 =fmaf(rl(X,OFF+i+0),W[i+0],B0 ); B1_=fmaf(rl(X,OFF+i+1),W[i+1],B1_); \
    B2_=fmaf(rl(X,OFF+i+2),W[i+2],B2_); B3_=fmaf(rl(X,OFF+i+3),W[i+3],B3_); }

#define EPART(X0,X1,X2,B0,B1_,B2_,B3_) \
  DOT32(X0, 0, wi0, B0,B1_,B2_,B3_) DOT32(X0,32, wi1, B0,B1_,B2_,B3_) \
  DOT32(X1, 0, wi2, B0,B1_,B2_,B3_) DOT32(X1,32, wi3, B0,B1_,B2_,B3_) \
  DOT32(X2, 0, wi4, B0,B1_,B2_,B3_) DOT32(X2,32, wi5, B0,B1_,B2_,B3_)

  // ---- prologue: e-part for t(0), emb regs for t(1) ----
  float acc_e;
  {
    const int tA = d ? 8191 : 0;
    const float* e = emb + (size_t)tA*768 + w*192 + l;
    float x0=e[0], x1=e[64], x2=e[128];
    float b0=0.f,b1=0.f,b2=0.f,b3=0.f;
    EPART(x0,x1,x2,b0,b1,b2,b3);
    acc_e = (b0+b1)+(b2+b3);
  }
  float ev0,ev1,ev2;
  {
    const int tB = d ? 8190 : 1;
    const float* e = emb + (size_t)tB*768 + w*192 + l;
    ev0=e[0]; ev1=e[64]; ev2=e[128];
  }

  for (int s=0; s<8192; s++){
    const int t  = d ? (8191-s) : s;
    const int pb = s & 1;
    // ---- h-part GEMV (recurrent matvec), seeded with acc_e ----
    float a0=acc_e, a1=0.f, a2=0.f, a3=0.f;
    DOT32(hv0, 0, wr0, a0,a1,a2,a3)
    DOT32(hv0,32, wr1, a0,a1,a2,a3)
    DOT32(hv1, 0, wr2, a0,a1,a2,a3)
    DOT32(hv1,32, wr3, a0,a1,a2,a3)
    part[pb][w][l] = (a0+a1)+(a2+a3);
    __syncthreads();

    if (w==0){
      float r = part[pb][0][l]+part[pb][1][l]+part[pb][2][l]+part[pb][3][l] + bias;
      const bool isg = ((l&3)==2);
      float xx = isg ? 2.f*r : r;
      float sg = 1.f/(1.f + expf(-xx));        // sigmoid
      float a  = isg ? fmaf(2.f,sg,-1.f) : sg; // tanh via 2*sig(2x)-1 for g-gate
      const int lb = l & ~3;
      float ig = __shfl(a, lb);
      float fg = __shfl(a, lb+1);
      float gg = __shfl(a, lb+2);
      float og = __shfl(a, lb+3);
      if ((l&3)==0){
        c = fmaf(fg, c, ig*gg);
        float h = og * tanhf(c);
        const int unit = k*16 + (l>>2);
        unsigned long long pk = ((unsigned long long)(unsigned)(s+1) << 32)
                              | (unsigned long long)__float_as_uint(h);
        __hip_atomic_store(hbuf + (pb<<10) + d*512 + unit, pk,
                           __ATOMIC_RELAXED, __HIP_MEMORY_SCOPE_AGENT);
        H[(size_t)t*1024 + d*512 + unit] = h;
      }
    }

    if (s<8191){
      // prefetch emb for t+2 (independent, in flight during EPART)
      float nx0=0.f, nx1=0.f, nx2=0.f;
      if (s<8190){
        const int t2 = d ? (8189-s) : (s+2);
        const float* e = emb + (size_t)t2*768 + w*192 + l;
        nx0=e[0]; nx1=e[64]; nx2=e[128];
      }
      // e-part for step s+1 — overlaps the publish->MALL propagation
      float b0=0.f,b1=0.f,b2=0.f,b3=0.f;
      EPART(ev0,ev1,ev2,b0,b1,b2,b3);
      acc_e = (b0+b1)+(b2+b3);
      ev0=nx0; ev1=nx1; ev2=nx2;

      // poll own two (tag,h) pairs — relaxed, no cache maintenance
      const unsigned long long* hp = hbuf + (pb<<10) + d*512 + w*128 + l;
      unsigned long long p0, p1;
      const unsigned want = (unsigned)(s+1);
      do {
        p0 = __hip_atomic_load(hp,    __ATOMIC_RELAXED, __HIP_MEMORY_SCOPE_AGENT);
        p1 = __hip_atomic_load(hp+64, __ATOMIC_RELAXED, __HIP_MEMORY_SCOPE_AGENT);
      } while ((unsigned)(p0>>32) < want || (unsigned)(p1>>32) < want);
      hv0 = __uint_as_float((unsigned)p0);
      hv1 = __uint_as_float((unsigned)p1);
    }
  }
#undef EPART
#undef DOT32
}

// =====================================================================
// K3: feats[t][n] = H[t][:] . w_tag[n][:] + b_tag[n]   (wave per row)
// =====================================================================
__global__ void feats_k(const float* __restrict__ H, const float* __restrict__ wtag,
                        const float* __restrict__ btag, float* __restrict__ feats)
{
  const int r = blockIdx.x*4 + (threadIdx.x>>6);
  const int l = threadIdx.x & 63;
  const float* hrow = H + (size_t)r*1024;
  float hv[16];
  #pragma unroll
  for (int j=0;j<16;j++) hv[j] = hrow[j*64 + l];
  #pragma unroll
  for (int n=0;n<5;n++){
    const float* wrow = wtag + n*1024;
    float acc = 0.f;
    #pragma unroll
    for (int j=0;j<16;j++) acc = fmaf(hv[j], wrow[j*64+l], acc);
    #pragma unroll
    for (int off=32; off; off>>=1) acc += __shfl_xor(acc, off);
    if (l==0) feats[r*5+n] = acc + btag[n];
  }
}

// =====================================================================
// V: sequential Viterbi forward (exact fp32, reference association order).
// =====================================================================
__global__ void vit_fv(const float* __restrict__ feats, const float* __restrict__ trans,
                       int* __restrict__ bps, float* __restrict__ out, int* __restrict__ ebest)
{
  const int l = threadIdx.x & 63;
  const bool active = (l < 25);
  const int n = l/5;
  float tr0=0,tr1=0,tr2=0,tr3=0,tr4=0;
  if (active){ tr0=trans[n*5+0]; tr1=trans[n*5+1]; tr2=trans[n*5+2]; tr3=trans[n*5+3]; tr4=trans[n*5+4]; }
  const float NEG = -10000.0f;
  float fv0=NEG, fv1=NEG, fv2=NEG, fv3=0.f, fv4=NEG;   // START=3

  float ring[16];
  #pragma unroll
  for (int j=0;j<16;j++) ring[j] = active ? feats[j*5+n] : 0.f;

  for (int tb=0; tb<8192; tb+=16){
    #pragma unroll
    for (int j=0;j<16;j++){
      const int t = tb + j;
      float ft = ring[j];
      float m = fv0 + tr0; int a = 0; float v;
      v = fv1 + tr1; if (v > m){ m=v; a=1; }
      v = fv2 + tr2; if (v > m){ m=v; a=2; }
      v = fv3 + tr3; if (v > m){ m=v; a=3; }
      v = fv4 + tr4; if (v > m){ m=v; a=4; }
      float fnew = m + ft;
      if (active && (l%5)==0) bps[t*5+n] = a;
      fv0 = __shfl(fnew, 0);  fv1 = __shfl(fnew, 5);  fv2 = __shfl(fnew, 10);
      fv3 = __shfl(fnew, 15); fv4 = __shfl(fnew, 20);
      const int tf = t + 16;
      ring[j] = (active && tf < 8192) ? feats[tf*5+n] : 0.f;
    }
  }
  if (l==0){
    float t0=trans[20], t1=trans[21], t2=trans[22], t3=trans[23], t4=trans[24];
    float m = fv0 + t0; int a = 0; float v;
    v = fv1 + t1; if (v > m){ m=v; a=1; }
    v = fv2 + t2; if (v > m){ m=v; a=2; }
    v = fv3 + t3; if (v > m){ m=v; a=3; }
    v = fv4 + t4; if (v > m){ m=v; a=4; }
    out[0] = m;       // path_score
    ebest[0] = a;
  }
}

// =====================================================================
// Backtrack: exact integer parallel scan over 256 chunks of 32 steps.
// =====================================================================
__global__ void bt_maps(const int* __restrict__ bps, int* __restrict__ Fc)
{
  __shared__ int sm[160];
  const int c = blockIdx.x, tid = threadIdx.x;
  for (int idx=tid; idx<160; idx+=64) sm[idx] = bps[c*160+idx];
  __syncthreads();
  if (tid<5){
    int cur = tid;
    for (int j=31;j>=0;j--) cur = sm[j*5+cur];
    Fc[c*5+tid] = cur;
  }
}

__global__ void bt_seq(const int* __restrict__ Fc, const int* __restrict__ ebest,
                       int* __restrict__ echunk)
{
  __shared__ int sm[1280];
  const int tid = threadIdx.x;
  for (int idx=tid; idx<1280; idx+=64) sm[idx]=Fc[idx];
  __syncthreads();
  if (tid==0){
    int e = ebest[0];
    for (int c=255;c>=0;c--){ echunk[c]=e; e = sm[c*5+e]; }
  }
}

__global__ void bt_emit(const int* __restrict__ bps, const int* __restrict__ echunk,
                        float* __restrict__ out)
{
  __shared__ int sm[160];
  const int c=blockIdx.x, tid=threadIdx.x;
  for (int idx=tid; idx<160; idx+=64) sm[idx]=bps[c*160+idx];
  __syncthreads();
  if (tid==0){
    int tag = echunk[c];
    out[1 + c*32 + 31] = (float)tag;
    for (int j=31;j>=1;j--){ tag = sm[j*5+tag]; out[1 + c*32 + j-1] = (float)tag; }
  }
}

// =====================================================================
extern "C" void kernel_launch(void* const* d_in, const int* in_sizes, int n_in,
                              void* d_out, int out_size, void* d_ws, size_t ws_size,
                              hipStream_t stream)
{
  (void)in_sizes; (void)n_in; (void)out_size; (void)ws_size;
  const float* emb  = (const float*)d_in[0];
  const float* wihf = (const float*)d_in[1];
  const float* whhf = (const float*)d_in[2];
  const float* bihf = (const float*)d_in[3];
  const float* bhhf = (const float*)d_in[4];
  const float* wihb = (const float*)d_in[5];
  const float* whhb = (const float*)d_in[6];
  const float* bihb = (const float*)d_in[7];
  const float* bhhb = (const float*)d_in[8];
  const float* wtag = (const float*)d_in[9];
  const float* btag = (const float*)d_in[10];
  const float* h0f  = (const float*)d_in[11];
  const float* c0f  = (const float*)d_in[12];
  const float* h0b  = (const float*)d_in[13];
  const float* c0b  = (const float*)d_in[14];
  const float* trans= (const float*)d_in[15];
  float* out = (float*)d_out;

  char* ws = (char*)d_ws;
  float* H      = (float*)(ws + OFF_H);
  float* feats  = (float*)(ws + OFF_FEATS);
  int*   bps    = (int*)  (ws + OFF_BPS);
  int*   Fc     = (int*)  (ws + OFF_FC);
  int*   echunk = (int*)  (ws + OFF_ECH);
  int*   ebest  = (int*)  (ws + OFF_EBEST);
  unsigned long long* hbuf = (unsigned long long*)(ws + OFF_HBUF);

  hipMemsetAsync(hbuf, 0, 2*1024*8, stream);   // clear (tag,h) pairs every launch

  lstm_k<<<64, 256, 0, stream>>>(emb, whhf, whhb, wihf, wihb,
                                 bihf, bhhf, bihb, bhhb,
                                 h0f, c0f, h0b, c0b, H, hbuf);
  feats_k<<<2048, 256, 0, stream>>>(H, wtag, btag, feats);
  vit_fv<<<1, 64, 0, stream>>>(feats, trans, bps, out, ebest);
  bt_maps<<<256, 64, 0, stream>>>(bps, Fc);
  bt_seq<<<1, 64, 0, stream>>>(Fc, ebest, echunk);
  bt_emit<<<256, 64, 0, stream>>>(bps, echunk, out);
}

// Round 4
// 16272.836 us; speedup vs baseline: 4.4922x; 1.4177x over previous
//
#include <hip/hip_runtime.h>
#include <hip/hip_bf16.h>
#include <math.h>

#define DEV static __device__ __forceinline__

DEV float rl(float v, int i){ return __uint_as_float(__builtin_amdgcn_readlane(__float_as_uint(v), i)); }

typedef float f32x16 __attribute__((ext_vector_type(16)));

// ---- workspace layout (bytes) ----
static constexpr size_t OFF_H     = 0;                    // 8192*1024*4 = 33554432
static constexpr size_t OFF_FEATS = 33554432;             // 8192*5*4    = 163840
static constexpr size_t OFF_BPS   = OFF_FEATS + 163840;   // 8192*5*4 int
static constexpr size_t OFF_FC    = OFF_BPS + 163840;     // 256*5*4
static constexpr size_t OFF_ECH   = OFF_FC + 5120;        // 256*4
static constexpr size_t OFF_EBEST = OFF_ECH + 1024;       // 256
static constexpr size_t OFF_HBUF  = OFF_EBEST + 256;      // 2*1024*8 = 16384 (u64, 8-aligned)

// =====================================================================
// K2: persistent BiLSTM. 64 blocks x 512 threads (8 waves).
// Blocks 0..31 forward, 32..63 backward. Block (d,k) owns hidden units
// [k*16,k*16+16) = 64 gate rows; lane l <-> gate row (l&3)*512+k*16+(l>>2).
// Waves split the 1280 dot-product columns: wave w takes whh cols
// [w*64,w*64+64) and wih cols [w*96,w*96+96) -> 160 weights/lane, held in
// 10 named f32x16 SSA values, asm-pinned so LLVM can't rematerialize
// (round-3: 320/lane > 256 addressable VGPRs -> remat -> 320KB/step L2
// re-stream -> 1.1us/step; VGPR_Count stuck at 184).
// Sync: h published as relaxed agent-scope u64 (tag<<32 | h_bits).
// =====================================================================
__global__ __launch_bounds__(512,2) void lstm_k(
    const float* __restrict__ emb,
    const float* __restrict__ whhf, const float* __restrict__ whhb,
    const float* __restrict__ wihf, const float* __restrict__ wihb,
    const float* __restrict__ bihf, const float* __restrict__ bhhf,
    const float* __restrict__ bihb, const float* __restrict__ bhhb,
    const float* __restrict__ h0f, const float* __restrict__ c0f,
    const float* __restrict__ h0b, const float* __restrict__ c0b,
    float* __restrict__ H, unsigned long long* __restrict__ hbuf)
{
  const int b  = blockIdx.x;
  const int d  = b >> 5;       // direction
  const int k  = b & 31;       // unit-group
  const int tid = threadIdx.x;
  const int w  = tid >> 6;     // wave 0..7
  const int l  = tid & 63;     // lane

  const float* whh = d ? whhb : whhf;
  const float* wih = d ? wihb : wihf;
  const int grow = (l&3)*512 + k*16 + (l>>2);   // global gate-row in [0,2048)

  // ---- resident weights: 10 x f32x16 named SSA values (160 VGPRs) ----
  const float* pr = whh + (size_t)grow*512 + w*64;
  f32x16 wr0 = *reinterpret_cast<const f32x16*>(pr);
  f32x16 wr1 = *reinterpret_cast<const f32x16*>(pr+16);
  f32x16 wr2 = *reinterpret_cast<const f32x16*>(pr+32);
  f32x16 wr3 = *reinterpret_cast<const f32x16*>(pr+48);
  const float* pi = wih + (size_t)grow*768 + w*96;
  f32x16 wi0 = *reinterpret_cast<const f32x16*>(pi);
  f32x16 wi1 = *reinterpret_cast<const f32x16*>(pi+16);
  f32x16 wi2 = *reinterpret_cast<const f32x16*>(pi+32);
  f32x16 wi3 = *reinterpret_cast<const f32x16*>(pi+48);
  f32x16 wi4 = *reinterpret_cast<const f32x16*>(pi+64);
  f32x16 wi5 = *reinterpret_cast<const f32x16*>(pi+80);
  // pin: values "modified" by asm -> cannot be rematerialized from memory
  asm volatile("" : "+v"(wr0)); asm volatile("" : "+v"(wr1));
  asm volatile("" : "+v"(wr2)); asm volatile("" : "+v"(wr3));
  asm volatile("" : "+v"(wi0)); asm volatile("" : "+v"(wi1));
  asm volatile("" : "+v"(wi2)); asm volatile("" : "+v"(wi3));
  asm volatile("" : "+v"(wi4)); asm volatile("" : "+v"(wi5));

  const float bias = (d?bihb:bihf)[grow] + (d?bhhb:bhhf)[grow];

  const float* h0 = d ? h0b : h0f;
  float hv = h0[w*64 + l];                 // this wave's h slice: 1 value/lane
  float c  = (d?c0b:c0f)[k*16 + (l>>2)];

  __shared__ float part[2][8][64];   // double-buffered cross-wave partials

#define DOT16(X, OFF, W, B0, B1_, B2_, B3_) \
  _Pragma("unroll") for (int i=0;i<16;i+=4){ \
    B0 =fmaf(rl(X,OFF+i+0),W[i+0],B0 ); B1_=fmaf(rl(X,OFF+i+1),W[i+1],B1_); \
    B2_=fmaf(rl(X,OFF+i+2),W[i+2],B2_); B3_=fmaf(rl(X,OFF+i+3),W[i+3],B3_); }

  // X0 carries wih cols w*96..+64 (all lanes), X1 cols +64..+96 (lanes 0..31)
#define EPART(X0,X1,B0,B1_,B2_,B3_) \
  DOT16(X0, 0, wi0, B0,B1_,B2_,B3_) DOT16(X0,16, wi1, B0,B1_,B2_,B3_) \
  DOT16(X0,32, wi2, B0,B1_,B2_,B3_) DOT16(X0,48, wi3, B0,B1_,B2_,B3_) \
  DOT16(X1, 0, wi4, B0,B1_,B2_,B3_) DOT16(X1,16, wi5, B0,B1_,B2_,B3_)

  // ---- prologue: e-part for t(0), emb regs for t(1) ----
  float acc_e;
  {
    const int tA = d ? 8191 : 0;
    const float* e = emb + (size_t)tA*768 + w*96 + l;
    float x0 = e[0];
    float x1 = (l<32) ? e[64] : 0.f;
    float b0=0.f,b1=0.f,b2=0.f,b3=0.f;
    EPART(x0,x1,b0,b1,b2,b3);
    acc_e = (b0+b1)+(b2+b3);
  }
  float ev0, ev1;
  {
    const int tB = d ? 8190 : 1;
    const float* e = emb + (size_t)tB*768 + w*96 + l;
    ev0 = e[0];
    ev1 = (l<32) ? e[64] : 0.f;
  }

  for (int s=0; s<8192; s++){
    const int t  = d ? (8191-s) : s;
    const int pb = s & 1;
    // ---- h-part GEMV (recurrent matvec), seeded with acc_e ----
    float a0=acc_e, a1=0.f, a2=0.f, a3=0.f;
    DOT16(hv, 0, wr0, a0,a1,a2,a3)
    DOT16(hv,16, wr1, a0,a1,a2,a3)
    DOT16(hv,32, wr2, a0,a1,a2,a3)
    DOT16(hv,48, wr3, a0,a1,a2,a3)
    part[pb][w][l] = (a0+a1)+(a2+a3);
    __syncthreads();

    if (w==0){
      float r = ((part[pb][0][l]+part[pb][1][l])+(part[pb][2][l]+part[pb][3][l]))
              + ((part[pb][4][l]+part[pb][5][l])+(part[pb][6][l]+part[pb][7][l])) + bias;
      const bool isg = ((l&3)==2);
      float xx = isg ? 2.f*r : r;
      float sg = 1.f/(1.f + expf(-xx));        // sigmoid
      float a  = isg ? fmaf(2.f,sg,-1.f) : sg; // tanh via 2*sig(2x)-1 for g-gate
      const int lb = l & ~3;
      float ig = __shfl(a, lb);
      float fg = __shfl(a, lb+1);
      float gg = __shfl(a, lb+2);
      float og = __shfl(a, lb+3);
      if ((l&3)==0){
        c = fmaf(fg, c, ig*gg);
        float h = og * tanhf(c);
        const int unit = k*16 + (l>>2);
        unsigned long long pk = ((unsigned long long)(unsigned)(s+1) << 32)
                              | (unsigned long long)__float_as_uint(h);
        __hip_atomic_store(hbuf + (pb<<10) + d*512 + unit, pk,
                           __ATOMIC_RELAXED, __HIP_MEMORY_SCOPE_AGENT);
        H[(size_t)t*1024 + d*512 + unit] = h;
      }
    }

    if (s<8191){
      // prefetch emb for t+2 (independent, in flight during EPART)
      float nx0=0.f, nx1=0.f;
      if (s<8190){
        const int t2 = d ? (8189-s) : (s+2);
        const float* e = emb + (size_t)t2*768 + w*96 + l;
        nx0 = e[0];
        nx1 = (l<32) ? e[64] : 0.f;
      }
      // e-part for step s+1 — overlaps the publish->MALL propagation
      float b0=0.f,b1=0.f,b2=0.f,b3=0.f;
      EPART(ev0,ev1,b0,b1,b2,b3);
      acc_e = (b0+b1)+(b2+b3);
      ev0=nx0; ev1=nx1;

      // poll own (tag,h) pair — relaxed, no cache maintenance
      const unsigned long long* hp = hbuf + (pb<<10) + d*512 + w*64 + l;
      const unsigned want = (unsigned)(s+1);
      unsigned long long p0 = __hip_atomic_load(hp, __ATOMIC_RELAXED, __HIP_MEMORY_SCOPE_AGENT);
      while ((unsigned)(p0>>32) < want){
        __builtin_amdgcn_s_sleep(1);
        p0 = __hip_atomic_load(hp, __ATOMIC_RELAXED, __HIP_MEMORY_SCOPE_AGENT);
      }
      hv = __uint_as_float((unsigned)p0);
    }
  }
#undef EPART
#undef DOT16
}

// =====================================================================
// K3: feats[t][n] = H[t][:] . w_tag[n][:] + b_tag[n]   (wave per row)
// =====================================================================
__global__ void feats_k(const float* __restrict__ H, const float* __restrict__ wtag,
                        const float* __restrict__ btag, float* __restrict__ feats)
{
  const int r = blockIdx.x*4 + (threadIdx.x>>6);
  const int l = threadIdx.x & 63;
  const float* hrow = H + (size_t)r*1024;
  float hv[16];
  #pragma unroll
  for (int j=0;j<16;j++) hv[j] = hrow[j*64 + l];
  #pragma unroll
  for (int n=0;n<5;n++){
    const float* wrow = wtag + n*1024;
    float acc = 0.f;
    #pragma unroll
    for (int j=0;j<16;j++) acc = fmaf(hv[j], wrow[j*64+l], acc);
    #pragma unroll
    for (int off=32; off; off>>=1) acc += __shfl_xor(acc, off);
    if (l==0) feats[r*5+n] = acc + btag[n];
  }
}

// =====================================================================
// V: sequential Viterbi forward (exact fp32, reference association order).
// =====================================================================
__global__ void vit_fv(const float* __restrict__ feats, const float* __restrict__ trans,
                       int* __restrict__ bps, float* __restrict__ out, int* __restrict__ ebest)
{
  const int l = threadIdx.x & 63;
  const bool active = (l < 25);
  const int n = l/5;
  float tr0=0,tr1=0,tr2=0,tr3=0,tr4=0;
  if (active){ tr0=trans[n*5+0]; tr1=trans[n*5+1]; tr2=trans[n*5+2]; tr3=trans[n*5+3]; tr4=trans[n*5+4]; }
  const float NEG = -10000.0f;
  float fv0=NEG, fv1=NEG, fv2=NEG, fv3=0.f, fv4=NEG;   // START=3

  float ring[16];
  #pragma unroll
  for (int j=0;j<16;j++) ring[j] = active ? feats[j*5+n] : 0.f;

  for (int tb=0; tb<8192; tb+=16){
    #pragma unroll
    for (int j=0;j<16;j++){
      const int t = tb + j;
      float ft = ring[j];
      float m = fv0 + tr0; int a = 0; float v;
      v = fv1 + tr1; if (v > m){ m=v; a=1; }
      v = fv2 + tr2; if (v > m){ m=v; a=2; }
      v = fv3 + tr3; if (v > m){ m=v; a=3; }
      v = fv4 + tr4; if (v > m){ m=v; a=4; }
      float fnew = m + ft;
      if (active && (l%5)==0) bps[t*5+n] = a;
      fv0 = __shfl(fnew, 0);  fv1 = __shfl(fnew, 5);  fv2 = __shfl(fnew, 10);
      fv3 = __shfl(fnew, 15); fv4 = __shfl(fnew, 20);
      const int tf = t + 16;
      ring[j] = (active && tf < 8192) ? feats[tf*5+n] : 0.f;
    }
  }
  if (l==0){
    float t0=trans[20], t1=trans[21], t2=trans[22], t3=trans[23], t4=trans[24];
    float m = fv0 + t0; int a = 0; float v;
    v = fv1 + t1; if (v > m){ m=v; a=1; }
    v = fv2 + t2; if (v > m){ m=v; a=2; }
    v = fv3 + t3; if (v > m){ m=v; a=3; }
    v = fv4 + t4; if (v > m){ m=v; a=4; }
    out[0] = m;       // path_score
    ebest[0] = a;
  }
}

// =====================================================================
// Backtrack: exact integer parallel scan over 256 chunks of 32 steps.
// =====================================================================
__global__ void bt_maps(const int* __restrict__ bps, int* __restrict__ Fc)
{
  __shared__ int sm[160];
  const int c = blockIdx.x, tid = threadIdx.x;
  for (int idx=tid; idx<160; idx+=64) sm[idx] = bps[c*160+idx];
  __syncthreads();
  if (tid<5){
    int cur = tid;
    for (int j=31;j>=0;j--) cur = sm[j*5+cur];
    Fc[c*5+tid] = cur;
  }
}

__global__ void bt_seq(const int* __restrict__ Fc, const int* __restrict__ ebest,
                       int* __restrict__ echunk)
{
  __shared__ int sm[1280];
  const int tid = threadIdx.x;
  for (int idx=tid; idx<1280; idx+=64) sm[idx]=Fc[idx];
  __syncthreads();
  if (tid==0){
    int e = ebest[0];
    for (int c=255;c>=0;c--){ echunk[c]=e; e = sm[c*5+e]; }
  }
}

__global__ void bt_emit(const int* __restrict__ bps, const int* __restrict__ echunk,
                        float* __restrict__ out)
{
  __shared__ int sm[160];
  const int c=blockIdx.x, tid=threadIdx.x;
  for (int idx=tid; idx<160; idx+=64) sm[idx]=bps[c*160+idx];
  __syncthreads();
  if (tid==0){
    int tag = echunk[c];
    out[1 + c*32 + 31] = (float)tag;
    for (int j=31;j>=1;j--){ tag = sm[j*5+tag]; out[1 + c*32 + j-1] = (float)tag; }
  }
}

// =====================================================================
extern "C" void kernel_launch(void* const* d_in, const int* in_sizes, int n_in,
                              void* d_out, int out_size, void* d_ws, size_t ws_size,
                              hipStream_t stream)
{
  (void)in_sizes; (void)n_in; (void)out_size; (void)ws_size;
  const float* emb  = (const float*)d_in[0];
  const float* wihf = (const float*)d_in[1];
  const float* whhf = (const float*)d_in[2];
  const float* bihf = (const float*)d_in[3];
  const float* bhhf = (const float*)d_in[4];
  const float* wihb = (const float*)d_in[5];
  const float* whhb = (const float*)d_in[6];
  const float* bihb = (const float*)d_in[7];
  const float* bhhb = (const float*)d_in[8];
  const float* wtag = (const float*)d_in[9];
  const float* btag = (const float*)d_in[10];
  const float* h0f  = (const float*)d_in[11];
  const float* c0f  = (const float*)d_in[12];
  const float* h0b  = (const float*)d_in[13];
  const float* c0b  = (const float*)d_in[14];
  const float* trans= (const float*)d_in[15];
  float* out = (float*)d_out;

  char* ws = (char*)d_ws;
  float* H      = (float*)(ws + OFF_H);
  float* feats  = (float*)(ws + OFF_FEATS);
  int*   bps    = (int*)  (ws + OFF_BPS);
  int*   Fc     = (int*)  (ws + OFF_FC);
  int*   echunk = (int*)  (ws + OFF_ECH);
  int*   ebest  = (int*)  (ws + OFF_EBEST);
  unsigned long long* hbuf = (unsigned long long*)(ws + OFF_HBUF);

  hipMemsetAsync(hbuf, 0, 2*1024*8, stream);   // clear (tag,h) pairs every launch

  lstm_k<<<64, 512, 0, stream>>>(emb, whhf, whhb, wihf, wihb,
                                 bihf, bhhf, bihb, bhhb,
                                 h0f, c0f, h0b, c0b, H, hbuf);
  feats_k<<<2048, 256, 0, stream>>>(H, wtag, btag, feats);
  vit_fv<<<1, 64, 0, stream>>>(feats, trans, bps, out, ebest);
  bt_maps<<<256, 64, 0, stream>>>(bps, Fc);
  bt_seq<<<1, 64, 0, stream>>>(Fc, ebest, echunk);
  bt_emit<<<256, 64, 0, stream>>>(bps, echunk, out);
}

// Round 5
// 13826.723 us; speedup vs baseline: 5.2869x; 1.1769x over previous
//
#include <hip/hip_runtime.h>
#include <hip/hip_bf16.h>
#include <math.h>

#define DEV static __device__ __forceinline__

DEV float rl(float v, int i){ return __uint_as_float(__builtin_amdgcn_readlane(__float_as_uint(v), i)); }

typedef float f32x16 __attribute__((ext_vector_type(16)));

// ---- workspace layout (bytes) ----
static constexpr size_t OFF_H     = 0;                    // 8192*1024*4 = 33554432
static constexpr size_t OFF_FEATS = 33554432;             // 8192*5*4    = 163840
static constexpr size_t OFF_BPS   = OFF_FEATS + 163840;   // 8192*5*4 int
static constexpr size_t OFF_FC    = OFF_BPS + 163840;     // 256*5*4
static constexpr size_t OFF_ECH   = OFF_FC + 5120;        // 256*4
static constexpr size_t OFF_EBEST = OFF_ECH + 1024;       // 256
static constexpr size_t OFF_HBUF  = OFF_EBEST + 256;      // 2*1024*8 = 16384
static constexpr size_t OFF_XG    = OFF_HBUF + 16384;     // 2*8192*2048*4 = 134217728
static constexpr size_t XG_BYTES  = 2ull*8192*2048*4;

// =====================================================================
// XG: xg[d][t][row] = emb[t][:] . wih_d[row][:]   (fp32 tiled GEMM)
// 128x128 tile, BK=16, 256 threads, 8x8 micro-tile. grid (64, 32).
// n in [0,4096): d = n>>11, row = n&2047.
// =====================================================================
__global__ __launch_bounds__(256) void xg_k(const float* __restrict__ emb,
                                            const float* __restrict__ wihf,
                                            const float* __restrict__ wihb,
                                            float* __restrict__ xg)
{
  const int tm = blockIdx.x * 128;        // t-tile base
  const int tn = blockIdx.y * 128;        // n-tile base (dir boundary aligned)
  const int tid = threadIdx.x;
  const int ty = tid >> 4, tx = tid & 15;
  __shared__ float As[16][132], Bs[16][132];
  float acc[8][8];
  #pragma unroll
  for (int i=0;i<8;i++)
    #pragma unroll
    for (int j=0;j<8;j++) acc[i][j] = 0.f;

  const int m  = tid & 127;
  const int n  = tn + m;
  const float* wih = (n & 2048) ? wihb : wihf;
  const float* arow = emb + (size_t)(tm+m)*768;
  const float* brow = wih + (size_t)(n&2047)*768;
  const int kq = (tid >> 7) << 2;         // 0 or 4

  for (int k0=0; k0<768; k0+=16){
    #pragma unroll
    for (int r=0;r<2;r++){
      const int kk = kq + r*8;
      float4 v = *reinterpret_cast<const float4*>(arow + k0 + kk);
      As[kk+0][m]=v.x; As[kk+1][m]=v.y; As[kk+2][m]=v.z; As[kk+3][m]=v.w;
      float4 u = *reinterpret_cast<const float4*>(brow + k0 + kk);
      Bs[kk+0][m]=u.x; Bs[kk+1][m]=u.y; Bs[kk+2][m]=u.z; Bs[kk+3][m]=u.w;
    }
    __syncthreads();
    #pragma unroll
    for (int k=0;k<16;k++){
      float4 a0 = *reinterpret_cast<const float4*>(&As[k][ty*8]);
      float4 a1 = *reinterpret_cast<const float4*>(&As[k][ty*8+4]);
      float4 b0 = *reinterpret_cast<const float4*>(&Bs[k][tx*8]);
      float4 b1 = *reinterpret_cast<const float4*>(&Bs[k][tx*8+4]);
      float af[8] = {a0.x,a0.y,a0.z,a0.w,a1.x,a1.y,a1.z,a1.w};
      float bf[8] = {b0.x,b0.y,b0.z,b0.w,b1.x,b1.y,b1.z,b1.w};
      #pragma unroll
      for (int i=0;i<8;i++)
        #pragma unroll
        for (int j=0;j<8;j++) acc[i][j] = fmaf(af[i], bf[j], acc[i][j]);
    }
    __syncthreads();
  }

  const int dd = tn >> 11;                 // direction of this n-tile
  const int nb = tn & 2047;
  float* xgp = xg + (size_t)dd*8192*2048;
  #pragma unroll
  for (int i=0;i<8;i++){
    float* orow = xgp + (size_t)(tm+ty*8+i)*2048 + nb + tx*8;
    #pragma unroll
    for (int j=0;j<8;j+=4){
      float4 st = { acc[i][j], acc[i][j+1], acc[i][j+2], acc[i][j+3] };
      *reinterpret_cast<float4*>(orow + j) = st;
    }
  }
}

#define DOT16(X, OFF, W, B0, B1_, B2_, B3_) \
  _Pragma("unroll") for (int i=0;i<16;i+=4){ \
    B0 =fmaf(rl(X,OFF+i+0),W[i+0],B0 ); B1_=fmaf(rl(X,OFF+i+1),W[i+1],B1_); \
    B2_=fmaf(rl(X,OFF+i+2),W[i+2],B2_); B3_=fmaf(rl(X,OFF+i+3),W[i+3],B3_); }

// =====================================================================
// K2 (xg path): persistent BiLSTM, 64 blocks x 512 threads (8 waves).
// Only whh resident: 64 floats/lane in 4 named f32x16 (fits — round-4's
// VGPR=104 showed whh held, wih re-streamed; wih is now precomputed xg).
// Wave 0 prefetches xg[t] (256B/block/step) depth-2 during poll windows.
// Sync: relaxed agent-scope u64 (tag<<32 | h_bits), unchanged.
// =====================================================================
__global__ __launch_bounds__(512,2) void lstm_xg(
    const float* __restrict__ whhf, const float* __restrict__ whhb,
    const float* __restrict__ bihf, const float* __restrict__ bhhf,
    const float* __restrict__ bihb, const float* __restrict__ bhhb,
    const float* __restrict__ h0f, const float* __restrict__ c0f,
    const float* __restrict__ h0b, const float* __restrict__ c0b,
    const float* __restrict__ xg,
    float* __restrict__ H, unsigned long long* __restrict__ hbuf)
{
  const int b  = blockIdx.x;
  const int d  = b >> 5;
  const int k  = b & 31;
  const int tid = threadIdx.x;
  const int w  = tid >> 6;
  const int l  = tid & 63;

  const float* whh = d ? whhb : whhf;
  const int grow = (l&3)*512 + k*16 + (l>>2);

  const float* pr = whh + (size_t)grow*512 + w*64;
  f32x16 wr0 = *reinterpret_cast<const f32x16*>(pr);
  f32x16 wr1 = *reinterpret_cast<const f32x16*>(pr+16);
  f32x16 wr2 = *reinterpret_cast<const f32x16*>(pr+32);
  f32x16 wr3 = *reinterpret_cast<const f32x16*>(pr+48);
  asm volatile("" : "+v"(wr0)); asm volatile("" : "+v"(wr1));
  asm volatile("" : "+v"(wr2)); asm volatile("" : "+v"(wr3));

  const float bias = (d?bihb:bihf)[grow] + (d?bhhb:bhhf)[grow];
  const float* xgp = xg + (size_t)d*8192*2048;

  const float* h0 = d ? h0b : h0f;
  float hv = h0[w*64 + l];
  float c  = (d?c0b:c0f)[k*16 + (l>>2)];

  __shared__ float part[2][8][64];

  float xq0 = 0.f, xq1 = 0.f;
  if (w==0){
    xq0 = xgp[(size_t)(d?8191:0)*2048 + grow];
    xq1 = xgp[(size_t)(d?8190:1)*2048 + grow];
  }

  for (int s=0; s<8192; s++){
    const int t  = d ? (8191-s) : s;
    const int pb = s & 1;
    float a0=0.f, a1=0.f, a2=0.f, a3=0.f;
    DOT16(hv, 0, wr0, a0,a1,a2,a3)
    DOT16(hv,16, wr1, a0,a1,a2,a3)
    DOT16(hv,32, wr2, a0,a1,a2,a3)
    DOT16(hv,48, wr3, a0,a1,a2,a3)
    part[pb][w][l] = (a0+a1)+(a2+a3);
    __syncthreads();

    if (w==0){
      float r = ((part[pb][0][l]+part[pb][1][l])+(part[pb][2][l]+part[pb][3][l]))
              + ((part[pb][4][l]+part[pb][5][l])+(part[pb][6][l]+part[pb][7][l]))
              + bias + xq0;
      const bool isg = ((l&3)==2);
      float xx = isg ? 2.f*r : r;
      float sg = 1.f/(1.f + expf(-xx));        // sigmoid
      float a  = isg ? fmaf(2.f,sg,-1.f) : sg; // tanh via 2*sig(2x)-1 for g-gate
      const int lb = l & ~3;
      float ig = __shfl(a, lb);
      float fg = __shfl(a, lb+1);
      float gg = __shfl(a, lb+2);
      float og = __shfl(a, lb+3);
      if ((l&3)==0){
        c = fmaf(fg, c, ig*gg);
        float h = og * tanhf(c);
        const int unit = k*16 + (l>>2);
        unsigned long long pk = ((unsigned long long)(unsigned)(s+1) << 32)
                              | (unsigned long long)__float_as_uint(h);
        __hip_atomic_store(hbuf + (pb<<10) + d*512 + unit, pk,
                           __ATOMIC_RELAXED, __HIP_MEMORY_SCOPE_AGENT);
        H[(size_t)t*1024 + d*512 + unit] = h;
      }
      // depth-2 xg prefetch: load for t(s+2) now; consumed at gate stage s+2.
      xq0 = xq1;
      if (s<8190) xq1 = xgp[(size_t)(d?(8189-s):(s+2))*2048 + grow];
    }

    if (s<8191){
      const unsigned long long* hp = hbuf + (pb<<10) + d*512 + w*64 + l;
      const unsigned want = (unsigned)(s+1);
      unsigned long long p0 = __hip_atomic_load(hp, __ATOMIC_RELAXED, __HIP_MEMORY_SCOPE_AGENT);
      while ((unsigned)(p0>>32) < want){
        __builtin_amdgcn_s_sleep(1);
        p0 = __hip_atomic_load(hp, __ATOMIC_RELAXED, __HIP_MEMORY_SCOPE_AGENT);
      }
      hv = __uint_as_float((unsigned)p0);
    }
  }
}

// =====================================================================
// Legacy fallback (exact round-4 kernel) — used only if ws_size too small.
// =====================================================================
__global__ __launch_bounds__(512,2) void lstm_legacy(
    const float* __restrict__ emb,
    const float* __restrict__ whhf, const float* __restrict__ whhb,
    const float* __restrict__ wihf, const float* __restrict__ wihb,
    const float* __restrict__ bihf, const float* __restrict__ bhhf,
    const float* __restrict__ bihb, const float* __restrict__ bhhb,
    const float* __restrict__ h0f, const float* __restrict__ c0f,
    const float* __restrict__ h0b, const float* __restrict__ c0b,
    float* __restrict__ H, unsigned long long* __restrict__ hbuf)
{
  const int b  = blockIdx.x;
  const int d  = b >> 5;
  const int k  = b & 31;
  const int tid = threadIdx.x;
  const int w  = tid >> 6;
  const int l  = tid & 63;

  const float* whh = d ? whhb : whhf;
  const float* wih = d ? wihb : wihf;
  const int grow = (l&3)*512 + k*16 + (l>>2);

  const float* pr = whh + (size_t)grow*512 + w*64;
  f32x16 wr0 = *reinterpret_cast<const f32x16*>(pr);
  f32x16 wr1 = *reinterpret_cast<const f32x16*>(pr+16);
  f32x16 wr2 = *reinterpret_cast<const f32x16*>(pr+32);
  f32x16 wr3 = *reinterpret_cast<const f32x16*>(pr+48);
  const float* pi = wih + (size_t)grow*768 + w*96;
  f32x16 wi0 = *reinterpret_cast<const f32x16*>(pi);
  f32x16 wi1 = *reinterpret_cast<const f32x16*>(pi+16);
  f32x16 wi2 = *reinterpret_cast<const f32x16*>(pi+32);
  f32x16 wi3 = *reinterpret_cast<const f32x16*>(pi+48);
  f32x16 wi4 = *reinterpret_cast<const f32x16*>(pi+64);
  f32x16 wi5 = *reinterpret_cast<const f32x16*>(pi+80);
  asm volatile("" : "+v"(wr0)); asm volatile("" : "+v"(wr1));
  asm volatile("" : "+v"(wr2)); asm volatile("" : "+v"(wr3));
  asm volatile("" : "+v"(wi0)); asm volatile("" : "+v"(wi1));
  asm volatile("" : "+v"(wi2)); asm volatile("" : "+v"(wi3));
  asm volatile("" : "+v"(wi4)); asm volatile("" : "+v"(wi5));

  const float bias = (d?bihb:bihf)[grow] + (d?bhhb:bhhf)[grow];
  const float* h0 = d ? h0b : h0f;
  float hv = h0[w*64 + l];
  float c  = (d?c0b:c0f)[k*16 + (l>>2)];

  __shared__ float part[2][8][64];

#define EPART(X0,X1,B0,B1_,B2_,B3_) \
  DOT16(X0, 0, wi0, B0,B1_,B2_,B3_) DOT16(X0,16, wi1, B0,B1_,B2_,B3_) \
  DOT16(X0,32, wi2, B0,B1_,B2_,B3_) DOT16(X0,48, wi3, B0,B1_,B2_,B3_) \
  DOT16(X1, 0, wi4, B0,B1_,B2_,B3_) DOT16(X1,16, wi5, B0,B1_,B2_,B3_)

  float acc_e;
  {
    const int tA = d ? 8191 : 0;
    const float* e = emb + (size_t)tA*768 + w*96 + l;
    float x0 = e[0];
    float x1 = (l<32) ? e[64] : 0.f;
    float b0=0.f,b1=0.f,b2=0.f,b3=0.f;
    EPART(x0,x1,b0,b1,b2,b3);
    acc_e = (b0+b1)+(b2+b3);
  }
  float ev0, ev1;
  {
    const int tB = d ? 8190 : 1;
    const float* e = emb + (size_t)tB*768 + w*96 + l;
    ev0 = e[0];
    ev1 = (l<32) ? e[64] : 0.f;
  }

  for (int s=0; s<8192; s++){
    const int t  = d ? (8191-s) : s;
    const int pb = s & 1;
    float a0=acc_e, a1=0.f, a2=0.f, a3=0.f;
    DOT16(hv, 0, wr0, a0,a1,a2,a3)
    DOT16(hv,16, wr1, a0,a1,a2,a3)
    DOT16(hv,32, wr2, a0,a1,a2,a3)
    DOT16(hv,48, wr3, a0,a1,a2,a3)
    part[pb][w][l] = (a0+a1)+(a2+a3);
    __syncthreads();

    if (w==0){
      float r = ((part[pb][0][l]+part[pb][1][l])+(part[pb][2][l]+part[pb][3][l]))
              + ((part[pb][4][l]+part[pb][5][l])+(part[pb][6][l]+part[pb][7][l])) + bias;
      const bool isg = ((l&3)==2);
      float xx = isg ? 2.f*r : r;
      float sg = 1.f/(1.f + expf(-xx));
      float a  = isg ? fmaf(2.f,sg,-1.f) : sg;
      const int lb = l & ~3;
      float ig = __shfl(a, lb);
      float fg = __shfl(a, lb+1);
      float gg = __shfl(a, lb+2);
      float og = __shfl(a, lb+3);
      if ((l&3)==0){
        c = fmaf(fg, c, ig*gg);
        float h = og * tanhf(c);
        const int unit = k*16 + (l>>2);
        unsigned long long pk = ((unsigned long long)(unsigned)(s+1) << 32)
                              | (unsigned long long)__float_as_uint(h);
        __hip_atomic_store(hbuf + (pb<<10) + d*512 + unit, pk,
                           __ATOMIC_RELAXED, __HIP_MEMORY_SCOPE_AGENT);
        H[(size_t)t*1024 + d*512 + unit] = h;
      }
    }

    if (s<8191){
      float nx0=0.f, nx1=0.f;
      if (s<8190){
        const int t2 = d ? (8189-s) : (s+2);
        const float* e = emb + (size_t)t2*768 + w*96 + l;
        nx0 = e[0];
        nx1 = (l<32) ? e[64] : 0.f;
      }
      float b0=0.f,b1=0.f,b2=0.f,b3=0.f;
      EPART(ev0,ev1,b0,b1,b2,b3);
      acc_e = (b0+b1)+(b2+b3);
      ev0=nx0; ev1=nx1;

      const unsigned long long* hp = hbuf + (pb<<10) + d*512 + w*64 + l;
      const unsigned want = (unsigned)(s+1);
      unsigned long long p0 = __hip_atomic_load(hp, __ATOMIC_RELAXED, __HIP_MEMORY_SCOPE_AGENT);
      while ((unsigned)(p0>>32) < want){
        __builtin_amdgcn_s_sleep(1);
        p0 = __hip_atomic_load(hp, __ATOMIC_RELAXED, __HIP_MEMORY_SCOPE_AGENT);
      }
      hv = __uint_as_float((unsigned)p0);
    }
  }
#undef EPART
}

// =====================================================================
// K3: feats[t][n] = H[t][:] . w_tag[n][:] + b_tag[n]   (wave per row)
// =====================================================================
__global__ void feats_k(const float* __restrict__ H, const float* __restrict__ wtag,
                        const float* __restrict__ btag, float* __restrict__ feats)
{
  const int r = blockIdx.x*4 + (threadIdx.x>>6);
  const int l = threadIdx.x & 63;
  const float* hrow = H + (size_t)r*1024;
  float hv[16];
  #pragma unroll
  for (int j=0;j<16;j++) hv[j] = hrow[j*64 + l];
  #pragma unroll
  for (int n=0;n<5;n++){
    const float* wrow = wtag + n*1024;
    float acc = 0.f;
    #pragma unroll
    for (int j=0;j<16;j++) acc = fmaf(hv[j], wrow[j*64+l], acc);
    #pragma unroll
    for (int off=32; off; off>>=1) acc += __shfl_xor(acc, off);
    if (l==0) feats[r*5+n] = acc + btag[n];
  }
}

// =====================================================================
// V: sequential Viterbi forward (exact fp32, reference association order).
// =====================================================================
__global__ void vit_fv(const float* __restrict__ feats, const float* __restrict__ trans,
                       int* __restrict__ bps, float* __restrict__ out, int* __restrict__ ebest)
{
  const int l = threadIdx.x & 63;
  const bool active = (l < 25);
  const int n = l/5;
  float tr0=0,tr1=0,tr2=0,tr3=0,tr4=0;
  if (active){ tr0=trans[n*5+0]; tr1=trans[n*5+1]; tr2=trans[n*5+2]; tr3=trans[n*5+3]; tr4=trans[n*5+4]; }
  const float NEG = -10000.0f;
  float fv0=NEG, fv1=NEG, fv2=NEG, fv3=0.f, fv4=NEG;   // START=3

  float ring[16];
  #pragma unroll
  for (int j=0;j<16;j++) ring[j] = active ? feats[j*5+n] : 0.f;

  for (int tb=0; tb<8192; tb+=16){
    #pragma unroll
    for (int j=0;j<16;j++){
      const int t = tb + j;
      float ft = ring[j];
      float m = fv0 + tr0; int a = 0; float v;
      v = fv1 + tr1; if (v > m){ m=v; a=1; }
      v = fv2 + tr2; if (v > m){ m=v; a=2; }
      v = fv3 + tr3; if (v > m){ m=v; a=3; }
      v = fv4 + tr4; if (v > m){ m=v; a=4; }
      float fnew = m + ft;
      if (active && (l%5)==0) bps[t*5+n] = a;
      fv0 = __shfl(fnew, 0);  fv1 = __shfl(fnew, 5);  fv2 = __shfl(fnew, 10);
      fv3 = __shfl(fnew, 15); fv4 = __shfl(fnew, 20);
      const int tf = t + 16;
      ring[j] = (active && tf < 8192) ? feats[tf*5+n] : 0.f;
    }
  }
  if (l==0){
    float t0=trans[20], t1=trans[21], t2=trans[22], t3=trans[23], t4=trans[24];
    float m = fv0 + t0; int a = 0; float v;
    v = fv1 + t1; if (v > m){ m=v; a=1; }
    v = fv2 + t2; if (v > m){ m=v; a=2; }
    v = fv3 + t3; if (v > m){ m=v; a=3; }
    v = fv4 + t4; if (v > m){ m=v; a=4; }
    out[0] = m;       // path_score
    ebest[0] = a;
  }
}

// =====================================================================
// Backtrack: exact integer parallel scan over 256 chunks of 32 steps.
// =====================================================================
__global__ void bt_maps(const int* __restrict__ bps, int* __restrict__ Fc)
{
  __shared__ int sm[160];
  const int c = blockIdx.x, tid = threadIdx.x;
  for (int idx=tid; idx<160; idx+=64) sm[idx] = bps[c*160+idx];
  __syncthreads();
  if (tid<5){
    int cur = tid;
    for (int j=31;j>=0;j--) cur = sm[j*5+cur];
    Fc[c*5+tid] = cur;
  }
}

__global__ void bt_seq(const int* __restrict__ Fc, const int* __restrict__ ebest,
                       int* __restrict__ echunk)
{
  __shared__ int sm[1280];
  const int tid = threadIdx.x;
  for (int idx=tid; idx<1280; idx+=64) sm[idx]=Fc[idx];
  __syncthreads();
  if (tid==0){
    int e = ebest[0];
    for (int c=255;c>=0;c--){ echunk[c]=e; e = sm[c*5+e]; }
  }
}

__global__ void bt_emit(const int* __restrict__ bps, const int* __restrict__ echunk,
                        float* __restrict__ out)
{
  __shared__ int sm[160];
  const int c=blockIdx.x, tid=threadIdx.x;
  for (int idx=tid; idx<160; idx+=64) sm[idx]=bps[c*160+idx];
  __syncthreads();
  if (tid==0){
    int tag = echunk[c];
    out[1 + c*32 + 31] = (float)tag;
    for (int j=31;j>=1;j--){ tag = sm[j*5+tag]; out[1 + c*32 + j-1] = (float)tag; }
  }
}

// =====================================================================
extern "C" void kernel_launch(void* const* d_in, const int* in_sizes, int n_in,
                              void* d_out, int out_size, void* d_ws, size_t ws_size,
                              hipStream_t stream)
{
  (void)in_sizes; (void)n_in; (void)out_size;
  const float* emb  = (const float*)d_in[0];
  const float* wihf = (const float*)d_in[1];
  const float* whhf = (const float*)d_in[2];
  const float* bihf = (const float*)d_in[3];
  const float* bhhf = (const float*)d_in[4];
  const float* wihb = (const float*)d_in[5];
  const float* whhb = (const float*)d_in[6];
  const float* bihb = (const float*)d_in[7];
  const float* bhhb = (const float*)d_in[8];
  const float* wtag = (const float*)d_in[9];
  const float* btag = (const float*)d_in[10];
  const float* h0f  = (const float*)d_in[11];
  const float* c0f  = (const float*)d_in[12];
  const float* h0b  = (const float*)d_in[13];
  const float* c0b  = (const float*)d_in[14];
  const float* trans= (const float*)d_in[15];
  float* out = (float*)d_out;

  char* ws = (char*)d_ws;
  float* H      = (float*)(ws + OFF_H);
  float* feats  = (float*)(ws + OFF_FEATS);
  int*   bps    = (int*)  (ws + OFF_BPS);
  int*   Fc     = (int*)  (ws + OFF_FC);
  int*   echunk = (int*)  (ws + OFF_ECH);
  int*   ebest  = (int*)  (ws + OFF_EBEST);
  unsigned long long* hbuf = (unsigned long long*)(ws + OFF_HBUF);
  float* xg     = (float*)(ws + OFF_XG);

  hipMemsetAsync(hbuf, 0, 2*1024*8, stream);   // clear (tag,h) pairs every launch

  const bool use_xg = ws_size >= OFF_XG + XG_BYTES;
  if (use_xg){
    xg_k<<<dim3(64,32), 256, 0, stream>>>(emb, wihf, wihb, xg);
    lstm_xg<<<64, 512, 0, stream>>>(whhf, whhb, bihf, bhhf, bihb, bhhb,
                                    h0f, c0f, h0b, c0b, xg, H, hbuf);
  } else {
    lstm_legacy<<<64, 512, 0, stream>>>(emb, whhf, whhb, wihf, wihb,
                                        bihf, bhhf, bihb, bhhb,
                                        h0f, c0f, h0b, c0b, H, hbuf);
  }
  feats_k<<<2048, 256, 0, stream>>>(H, wtag, btag, feats);
  vit_fv<<<1, 64, 0, stream>>>(feats, trans, bps, out, ebest);
  bt_maps<<<256, 64, 0, stream>>>(bps, Fc);
  bt_seq<<<1, 64, 0, stream>>>(Fc, ebest, echunk);
  bt_emit<<<256, 64, 0, stream>>>(bps, echunk, out);
}